// Round 12
// baseline (544.351 us; speedup 1.0000x reference)
//
#include <hip/hip_runtime.h>
#include <hip/hip_bf16.h>
#include <hip/hip_cooperative_groups.h>
#include <math.h>

namespace cg = cooperative_groups;

typedef __bf16 bf16;
typedef signed char i8;
typedef __bf16 bf16x8 __attribute__((ext_vector_type(8)));
typedef __bf16 bf16x4 __attribute__((ext_vector_type(4)));
typedef signed char i8x4 __attribute__((ext_vector_type(4)));
typedef signed char i8x8 __attribute__((ext_vector_type(8)));
typedef int    i32x4 __attribute__((ext_vector_type(4)));
typedef float  f32x4  __attribute__((ext_vector_type(4)));
typedef float  f32x16 __attribute__((ext_vector_type(16)));
typedef unsigned int u32x4 __attribute__((ext_vector_type(4)));

static constexpr int B_  = 2;
static constexpr int S_  = 2048;
static constexpr int D_  = 1024;
static constexpr int H_  = 16;
static constexpr int HD_ = 64;
static constexpr int I_  = 4096;
static constexpr int NT  = B_ * S_;       // 4096 tokens

// ---------- helpers ----------
__device__ __forceinline__ void atomicMaxF(float* p, float v) {
  atomicMax((unsigned int*)p, __float_as_uint(v));   // v >= 0 always
}

__device__ __forceinline__ f32x16 mfma32(bf16x8 a, bf16x8 b, f32x16 c) {
  return __builtin_amdgcn_mfma_f32_32x32x16_bf16(a, b, c, 0, 0, 0);
}

__device__ __forceinline__ i32x4 mfma_i8(i32x4 a, i32x4 b, i32x4 c) {
  return __builtin_amdgcn_mfma_i32_16x16x64_i8(a, b, c, 0, 0, 0);
}

__device__ __forceinline__ void gload16(const void* g, void* lds) {
  __builtin_amdgcn_global_load_lds(
      (const __attribute__((address_space(1))) void*)g,
      (__attribute__((address_space(3))) void*)lds, 16, 0, 0);
}

__device__ __forceinline__ i8 quantn(float x, float scale, float qmax) {
  return (i8)(int)rintf(fminf(fmaxf(x / scale, -qmax), qmax));
}

// stage a 64x64 bf16 tile into LDS with a 128-thread block; XOR swizzle
// (chunk ^= row&7) applied on the GLOBAL source, LDS dest stays linear.
__device__ __forceinline__ void stage64b(const bf16* __restrict__ g, int rs, bf16* lds, int t) {
  #pragma unroll
  for (int r = 0; r < 4; r++) {
    const int cl  = r * 128 + t;           // 16B-chunk id in tile (512 total)
    const int row = cl >> 3;               // 8 chunks per 128B row
    const int scr = (cl & 7) ^ (row & 7);  // pre-swizzled source chunk
    gload16(g + (size_t)row * rs + scr * 8,
            (char*)lds + (size_t)(r * 128 + (t & 64)) * 16);
  }
}

// ---------- madd precompute + scalar-slot init ----------
__global__ __launch_bounds__(256) void k_prep(const float* __restrict__ mask,
                                              float* __restrict__ madd, float* __restrict__ scal) {
  constexpr float MSK2 = -14426.950408889634f;   // -10000 * log2(e)
  const int i = blockIdx.x * 256 + threadIdx.x;
  if (blockIdx.x == 0 && threadIdx.x < 32) scal[threadIdx.x] = 0.f;
  if (i < B_ * S_) madd[i] = (1.0f - mask[i]) * MSK2;
}

// ---------- fused per-tensor absmax + quant for the 6 weights (i8 out) -------
struct WArgs {
  const float* w[6];
  i8* q[6];
  size_t n4[6];
};

__global__ __launch_bounds__(256) void k_absmax6(WArgs a, float* __restrict__ slots) {
  const int z = blockIdx.z;
  const float* __restrict__ x = a.w[z];
  const size_t n4 = a.n4[z];
  size_t i = (size_t)blockIdx.x * 256 + threadIdx.x;
  const size_t stride = (size_t)gridDim.x * 256;
  float m = 0.f;
  for (; i < n4; i += stride) {
    float4 v = ((const float4*)x)[i];
    m = fmaxf(m, fmaxf(fmaxf(fabsf(v.x), fabsf(v.y)), fmaxf(fabsf(v.z), fabsf(v.w))));
  }
  #pragma unroll
  for (int o = 32; o; o >>= 1) m = fmaxf(m, __shfl_xor(m, o));
  __shared__ float red[4];
  if ((threadIdx.x & 63) == 0) red[threadIdx.x >> 6] = m;
  __syncthreads();
  if (threadIdx.x == 0)
    atomicMaxF(slots + z, fmaxf(fmaxf(red[0], red[1]), fmaxf(red[2], red[3])));
}

__global__ __launch_bounds__(256) void k_quant6(WArgs a, const float* __restrict__ slots,
                                                const int* __restrict__ bits) {
  const int z = blockIdx.z;
  const float* __restrict__ x = a.w[z];
  i8* __restrict__ y = a.q[z];
  const size_t n4 = a.n4[z];
  const float qmax  = (float)((1 << (*bits - 1)) - 1);
  const float scale = fmaxf(slots[z], 1e-8f) / qmax;
  size_t i = (size_t)blockIdx.x * 256 + threadIdx.x;
  const size_t stride = (size_t)gridDim.x * 256;
  for (; i < n4; i += stride) {
    float4 v = ((const float4*)x)[i];
    i8x4 o;
    o[0] = quantn(v.x, scale, qmax);
    o[1] = quantn(v.y, scale, qmax);
    o[2] = quantn(v.z, scale, qmax);
    o[3] = quantn(v.w, scale, qmax);
    ((i8x4*)y)[i] = o;
  }
}

// ---------- fake-quant fp32 -> i8 codes (attention output) ----------
__global__ __launch_bounds__(256) void k_quant(const float* __restrict__ x, i8* __restrict__ y,
                                               const float* __restrict__ slot,
                                               const int* __restrict__ bits, size_t n4) {
  const float qmax  = (float)((1 << (*bits - 1)) - 1);
  const float scale = fmaxf(*slot, 1e-8f) / qmax;
  size_t i = (size_t)blockIdx.x * 256 + threadIdx.x;
  const size_t stride = (size_t)gridDim.x * 256;
  for (; i < n4; i += stride) {
    float4 v = ((const float4*)x)[i];
    i8x4 o;
    o[0] = quantn(v.x, scale, qmax);
    o[1] = quantn(v.y, scale, qmax);
    o[2] = quantn(v.z, scale, qmax);
    o[3] = quantn(v.w, scale, qmax);
    ((i8x4*)y)[i] = o;
  }
}

// ---------- fake-quant bf16 (GELU out) -> i8 codes ----------
__global__ __launch_bounds__(256) void k_qgelu(const bf16* __restrict__ x, i8* __restrict__ y,
                                               const float* __restrict__ slot,
                                               const int* __restrict__ bits, size_t n8) {
  const float qmax  = (float)((1 << (*bits - 1)) - 1);
  const float scale = fmaxf(*slot, 1e-8f) / qmax;
  size_t i = (size_t)blockIdx.x * 256 + threadIdx.x;
  if (i >= n8) return;
  bf16x8 v = ((const bf16x8*)x)[i];
  i8x8 o;
  #pragma unroll
  for (int j = 0; j < 8; j++) o[j] = quantn((float)v[j], scale, qmax);
  ((i8x8*)y)[i] = o;
}

// ---------- COOPERATIVE fused LayerNorm -> absmax -> grid.sync -> quant ------
// 1024 blocks x 256 thr, 4 rows/block; fp32 LN values stay in REGISTERS across
// the grid sync (exact numerics, no fp32 round-trip through HBM).  Post-sync
// absmax read via atomicMax(p,0) (coherent across XCDs).
// Co-residency: ~48 VGPR, 32B LDS -> 4 blocks/CU needed << 8 capacity.
__global__ __launch_bounds__(256) void k_lnq(const float* __restrict__ x, const float* __restrict__ g,
                                             const float* __restrict__ be, i8* __restrict__ y,
                                             float* __restrict__ slot, const int* __restrict__ bits) {
  const int t = threadIdx.x;
  const int row0 = blockIdx.x * 4;
  __shared__ float red[8];
  const float4 gv = ((const float4*)g)[t];
  const float4 bv = ((const float4*)be)[t];
  float4 o[4];
  float lmax = 0.f;
  #pragma unroll
  for (int r = 0; r < 4; r++) {
    const float4 v = ((const float4*)(x + (size_t)(row0 + r) * D_))[t];
    float s = v.x + v.y + v.z + v.w;
    float q = v.x * v.x + v.y * v.y + v.z * v.z + v.w * v.w;
    #pragma unroll
    for (int oo = 32; oo; oo >>= 1) { s += __shfl_xor(s, oo); q += __shfl_xor(q, oo); }
    const int wid = t >> 6;
    if ((t & 63) == 0) { red[wid] = s; red[4 + wid] = q; }
    __syncthreads();
    s = red[0] + red[1] + red[2] + red[3];
    q = red[4] + red[5] + red[6] + red[7];
    __syncthreads();               // red reused next iteration
    const float mean = s * (1.f / D_);
    const float rstd = rsqrtf(q * (1.f / D_) - mean * mean + 1e-5f);
    o[r].x = (v.x - mean) * rstd * gv.x + bv.x;
    o[r].y = (v.y - mean) * rstd * gv.y + bv.y;
    o[r].z = (v.z - mean) * rstd * gv.z + bv.z;
    o[r].w = (v.w - mean) * rstd * gv.w + bv.w;
    lmax = fmaxf(lmax, fmaxf(fmaxf(fabsf(o[r].x), fabsf(o[r].y)),
                             fmaxf(fabsf(o[r].z), fabsf(o[r].w))));
  }
  #pragma unroll
  for (int oo = 32; oo; oo >>= 1) lmax = fmaxf(lmax, __shfl_xor(lmax, oo));
  if ((t & 63) == 0) red[t >> 6] = lmax;
  __syncthreads();
  if (t == 0) atomicMaxF(slot, fmaxf(fmaxf(red[0], red[1]), fmaxf(red[2], red[3])));
  __threadfence();
  cg::this_grid().sync();
  if (t == 0) red[0] = __uint_as_float(atomicMax((unsigned int*)slot, 0u));  // coherent read
  __syncthreads();
  const float qmax  = (float)((1 << (*bits - 1)) - 1);
  const float scale = fmaxf(red[0], 1e-8f) / qmax;
  #pragma unroll
  for (int r = 0; r < 4; r++) {
    i8x4 c;
    c[0] = quantn(o[r].x, scale, qmax);
    c[1] = quantn(o[r].y, scale, qmax);
    c[2] = quantn(o[r].z, scale, qmax);
    c[3] = quantn(o[r].w, scale, qmax);
    ((i8x4*)(y + (size_t)(row0 + r) * D_))[t] = c;
  }
}

// ---------- int8 GEMM body (round-10 proven): C = (A@B^T)*s_a*s_w + bias -----
// tile (MT*32)x128, BK=128 i8, 4 waves 2x2, double-buffered (stage t+1 before
// compute t, one barrier/step).  T2 chunk XOR-swizzle on the GLOBAL source.
// bx/by/bz decoded per call-site for XCD-aware L2 locality (XCD = bid%8).
struct GemmArgs {
  const i8* A;
  const i8* B0; const i8* B1; const i8* B2;
  const float* bias0; const float* bias1; const float* bias2;
  void* out0; void* out1; void* out2;
  const float* res;   // MODE 1: residual (fp32, same layout as out)
  float* slot;        // MODE 2: absmax slot
  const float* sa;                                   // activation absmax slot
  const float* sw0; const float* sw1; const float* sw2;  // weight absmax slots
  const int* abit; const int* wbit;
  int K; int ldc;
};

template <int MODE, int MT>
__device__ __forceinline__ void gemm_body(GemmArgs a, int bx, int by, int bz) {
  constexpr int TM = MT * 32;
  __shared__ __align__(16) i8 As[2][TM * 128];
  __shared__ __align__(16) i8 Bs[2][128 * 128];
  const int t = threadIdx.x, wid = t >> 6, lane = t & 63;
  const int grp = lane >> 4, l15 = lane & 15;
  const int wm = wid >> 1, wn = wid & 1;
  const size_t m0 = (size_t)bx * TM, n0 = (size_t)by * 128;
  const int K = a.K, ldc = a.ldc;

  const i8* Bw; const float* bias; void* outv; const float* swp;
  if constexpr (MODE == 0) {
    Bw   = bz == 0 ? a.B0 : (bz == 1 ? a.B1 : a.B2);
    bias = bz == 0 ? a.bias0 : (bz == 1 ? a.bias1 : a.bias2);
    outv = bz == 0 ? a.out0 : (bz == 1 ? a.out1 : a.out2);
    swp  = bz == 0 ? a.sw0 : (bz == 1 ? a.sw1 : a.sw2);
  } else {
    Bw = a.B0; bias = a.bias0; outv = a.out0; swp = a.sw0;
  }
  const float qa = (float)((1 << (*a.abit - 1)) - 1);
  const float qw = (float)((1 << (*a.wbit - 1)) - 1);
  const float sasw = (fmaxf(*a.sa, 1e-8f) / qa) * (fmaxf(*swp, 1e-8f) / qw);

  i32x4 acc[MT][4];
  #pragma unroll
  for (int m = 0; m < MT; m++)
    #pragma unroll
    for (int n = 0; n < 4; n++) acc[m][n] = i32x4{0, 0, 0, 0};

  auto stage = [&](int kt, int buf) {
    #pragma unroll
    for (int r = 0; r < MT; r++) {
      const int cl = r * 256 + t;
      const int row = cl >> 3, c = cl & 7;
      gload16(a.A + (m0 + row) * (size_t)K + kt + ((c ^ (row & 7)) * 16),
              (char*)&As[buf][0] + (size_t)(r * 256 + (t & 192)) * 16);
    }
    #pragma unroll
    for (int r = 0; r < 4; r++) {
      const int cl = r * 256 + t;
      const int row = cl >> 3, c = cl & 7;
      gload16(Bw + (n0 + row) * (size_t)K + kt + ((c ^ (row & 7)) * 16),
              (char*)&Bs[buf][0] + (size_t)(r * 256 + (t & 192)) * 16);
    }
  };

  stage(0, 0);
  __syncthreads();           // tile 0 resident
  int cur = 0;
  for (int kt = 0; kt < K; kt += 128) {
    if (kt + 128 < K) stage(kt + 128, cur ^ 1);  // prefetch next (covered by MFMA)
    #pragma unroll
    for (int ks = 0; ks < 2; ks++) {
      i32x4 bfv[4];
      #pragma unroll
      for (int n = 0; n < 4; n++) {
        const int rb = wn * 64 + n * 16 + l15;
        bfv[n] = *(const i32x4*)(&Bs[cur][0] + rb * 128 + (((ks * 4 + grp) ^ (rb & 7)) * 16));
      }
      #pragma unroll
      for (int m = 0; m < MT; m++) {
        const int ra = wm * (MT * 16) + m * 16 + l15;
        const i32x4 af = *(const i32x4*)(&As[cur][0] + ra * 128 + (((ks * 4 + grp) ^ (ra & 7)) * 16));
        #pragma unroll
        for (int n = 0; n < 4; n++)
          acc[m][n] = mfma_i8(af, bfv[n], acc[m][n]);
      }
    }
    __syncthreads();         // drains prefetch (vmcnt) + protects cur for rotate
    cur ^= 1;
  }

  // epilogue: C/D frag layout: row=(lane>>4)*4+i, col=lane&15
  const size_t gr0 = m0 + wm * (MT * 16) + grp * 4;
  const size_t gc0 = n0 + wn * 64 + l15;

  if constexpr (MODE == 0) {
    if (bz == 2) {
      // V^T store: out[b][gc][s] packed bf16x4 along s (i dimension)
      #pragma unroll
      for (int n = 0; n < 4; n++) {
        const size_t gc = gc0 + n * 16;
        const float bc = bias[gc];
        #pragma unroll
        for (int m = 0; m < MT; m++) {
          const size_t gr = gr0 + m * 16;              // tokens gr..gr+3, same batch
          const size_t bb = gr >> 11, s0 = gr & (S_ - 1);
          bf16x4 vv;
          #pragma unroll
          for (int i = 0; i < 4; i++) vv[i] = (bf16)((float)acc[m][n][i] * sasw + bc);
          *(bf16x4*)((bf16*)outv + bb * (size_t)D_ * S_ + gc * S_ + s0) = vv;
        }
      }
      return;
    }
  }

  float lmax = 0.f;
  #pragma unroll
  for (int n = 0; n < 4; n++) {
    const size_t gc = gc0 + n * 16;
    const float bc = bias[gc];
    #pragma unroll
    for (int m = 0; m < MT; m++) {
      const size_t gr = gr0 + m * 16;
      #pragma unroll
      for (int i = 0; i < 4; i++) {
        const float v = (float)acc[m][n][i] * sasw + bc;
        const size_t idx = (gr + i) * (size_t)ldc + gc;
        if constexpr (MODE == 0) {
          ((bf16*)outv)[idx] = (bf16)v;
        } else if constexpr (MODE == 1) {
          ((float*)outv)[idx] = v + a.res[idx];
        } else {
          const float gl = 0.5f * v * (1.0f + erff(v * 0.7071067811865475f));
          ((bf16*)outv)[idx] = (bf16)gl;
          lmax = fmaxf(lmax, fabsf(gl));
        }
      }
    }
  }
  if constexpr (MODE == 2) {
    #pragma unroll
    for (int o = 32; o; o >>= 1) lmax = fmaxf(lmax, __shfl_xor(lmax, o));
    float* red = (float*)&As[0][0];     // LDS reuse (k-loop done)
    if (lane == 0) red[wid] = lmax;
    __syncthreads();
    if (t == 0) atomicMaxF(a.slot, fmaxf(fmaxf(red[0], red[1]), fmaxf(red[2], red[3])));
  }
}

// Per-call-site wrappers: named for rocprof attribution; 1-D grid; block
// decode pins XCD (= bid%8) to an L2-resident working set.
__global__ __launch_bounds__(256) void k_gqkv(GemmArgs a) {
  const int d = blockIdx.x, c = d & 7, s = d >> 3;   // s in [0,96)
  gemm_body<0, 4>(a, s / 3, c, s % 3);
}
__global__ __launch_bounds__(256) void k_gout(GemmArgs a) {
  const int d = blockIdx.x, c = d & 7, s = d >> 3;   // s in [0,64)
  gemm_body<1, 2>(a, s, c, 0);
}
__global__ __launch_bounds__(256) void k_gmlp1(GemmArgs a) {
  const int d = blockIdx.x, c = d & 7, s = d >> 3;   // s in [0,128)
  gemm_body<2, 4>(a, s >> 2, c * 4 + (s & 3), 0);
}
__global__ __launch_bounds__(256) void k_gmlp2(GemmArgs a) {
  const int d = blockIdx.x, c = d & 7, s = d >> 3;   // s in [0,64)
  gemm_body<1, 2>(a, ((c >> 2) << 5) | (s >> 1), ((c & 3) << 1) | (s & 1), 0);
}

// ---------- fused attention (round-10 proven: flash, swapped 32x32 MFMA) -----
// 2 waves x 32 q; KV tile 64 double-buffered; swapped QK (mfma(K,Q)) -> scores
// lane-local, in-register softmax, defer-max (T13), cvt_pk+permlane pack (T12),
// swapped PV (mfma(V^T,P)).
__global__ __launch_bounds__(128) void k_attn(const bf16* __restrict__ qb, const bf16* __restrict__ kb,
                                              const bf16* __restrict__ vt, const float* __restrict__ madd,
                                              float* __restrict__ out, float* __restrict__ slot) {
  constexpr float SCL2 = 0.18033688011112042f;   // 0.125 * log2(e)  (exp2 domain)
  constexpr float THR  = 8.0f;                   // defer-max threshold (log2 units)
  __shared__ __align__(16) bf16 Ks[2][64 * 64];  // [buf][key][d]  (chunk-swizzled)
  __shared__ __align__(16) bf16 Vs[2][64 * 64];  // [buf][d][key]  (chunk-swizzled)
  __shared__ float red[2];
  const int t = threadIdx.x, wid = t >> 6, lane = t & 63;
  const int l31 = lane & 31, hi = lane >> 5;
  const int b = blockIdx.y >> 4, h = blockIdx.y & 15;   // H = 16
  const size_t qkbase = ((size_t)b * S_) * D_ + (size_t)h * HD_;
  const size_t vtbase = (size_t)b * D_ * S_ + (size_t)h * HD_ * S_;
  const int q = blockIdx.x * 64 + wid * 32 + l31;       // this lane's q-row

  bf16x8 qf[4];
  #pragma unroll
  for (int j = 0; j < 4; j++)
    qf[j] = *(const bf16x8*)(qb + qkbase + (size_t)q * D_ + j * 16 + hi * 8);

  f32x16 ao0, ao1;
  #pragma unroll
  for (int r = 0; r < 16; r++) { ao0[r] = 0.f; ao1[r] = 0.f; }
  float mi = -INFINITY, li = 0.f;

  stage64b(kb + qkbase, D_, Ks[0], t);
  stage64b(vt + vtbase, S_, Vs[0], t);
  __syncthreads();
  int cur = 0;

  const float* mp = madd + (size_t)b * S_ + hi * 4;

  for (int kt0 = 0; kt0 < S_; kt0 += 64) {
    // madd loads FIRST (vmcnt-oldest), fence, then prefetch
    f32x4 mv[2][4];
    #pragma unroll
    for (int kb2 = 0; kb2 < 2; kb2++)
      #pragma unroll
      for (int g = 0; g < 4; g++)
        mv[kb2][g] = *(const f32x4*)(mp + kt0 + kb2 * 32 + g * 8);
    __builtin_amdgcn_sched_barrier(0);
    if (kt0 + 64 < S_) {
      stage64b(kb + qkbase + (size_t)(kt0 + 64) * D_, D_, Ks[cur ^ 1], t);
      stage64b(vt + vtbase + (kt0 + 64), S_, Vs[cur ^ 1], t);
    }

    // QK^T swapped: D[row=key][col=q]
    f32x16 s0, s1;
    #pragma unroll
    for (int r = 0; r < 16; r++) { s0[r] = 0.f; s1[r] = 0.f; }
    #pragma unroll
    for (int j = 0; j < 4; j++) {
      const int ch = (j * 2 + hi);
      const bf16x8 kf0 = *(const bf16x8*)(&Ks[cur][0] + l31 * 64 + ((ch ^ (l31 & 7)) * 8));
      const bf16x8 kf1 = *(const bf16x8*)(&Ks[cur][0] + (32 + l31) * 64 + ((ch ^ (l31 & 7)) * 8));
      s0 = mfma32(kf0, qf[j], s0);
      s1 = mfma32(kf1, qf[j], s1);
    }

    float pv_[32];
    #pragma unroll
    for (int r = 0; r < 16; r++) pv_[r]      = s0[r] * SCL2 + mv[0][r >> 2][r & 3];
    #pragma unroll
    for (int r = 0; r < 16; r++) pv_[16 + r] = s1[r] * SCL2 + mv[1][r >> 2][r & 3];

    float mx = pv_[0];
    #pragma unroll
    for (int r = 1; r < 32; r++) mx = fmaxf(mx, pv_[r]);
    mx = fmaxf(mx, __shfl_xor(mx, 32));

    if (!__all(mx - mi <= THR)) {        // defer-max
      const float mnew = fmaxf(mi, mx);
      const float co = exp2f(mi - mnew);
      li *= co;
      #pragma unroll
      for (int r = 0; r < 16; r++) { ao0[r] *= co; ao1[r] *= co; }
      mi = mnew;
    }

    float ls = 0.f;
    #pragma unroll
    for (int r = 0; r < 32; r++) { pv_[r] = exp2f(pv_[r] - mi); ls += pv_[r]; }
    li += ls;

    unsigned pk[16];
    #pragma unroll
    for (int tt = 0; tt < 8; tt++) {
      asm("v_cvt_pk_bf16_f32 %0, %1, %2" : "=v"(pk[tt])     : "v"(pv_[2 * tt]),      "v"(pv_[2 * tt + 1]));
      asm("v_cvt_pk_bf16_f32 %0, %1, %2" : "=v"(pk[8 + tt]) : "v"(pv_[16 + 2 * tt]), "v"(pv_[16 + 2 * tt + 1]));
    }
    #pragma unroll
    for (int g = 0; g < 4; g++) {
      asm volatile("v_permlane32_swap_b32 %0, %1" : "+v"(pk[4 * g]),     "+v"(pk[4 * g + 2]));
      asm volatile("v_permlane32_swap_b32 %0, %1" : "+v"(pk[4 * g + 1]), "+v"(pk[4 * g + 3]));
    }

    #pragma unroll
    for (int j = 0; j < 4; j++) {
      const u32x4 w = {pk[4 * j], pk[4 * j + 1], pk[4 * j + 2], pk[4 * j + 3]};
      const bf16x8 pf = __builtin_bit_cast(bf16x8, w);
      const int ch = (j * 2 + hi);
      const bf16x8 vf0 = *(const bf16x8*)(&Vs[cur][0] + l31 * 64 + ((ch ^ (l31 & 7)) * 8));
      const bf16x8 vf1 = *(const bf16x8*)(&Vs[cur][0] + (32 + l31) * 64 + ((ch ^ (l31 & 7)) * 8));
      ao0 = mfma32(vf0, pf, ao0);
      ao1 = mfma32(vf1, pf, ao1);
    }
    __syncthreads();   // prefetch landed + all waves done reading cur
    cur ^= 1;
  }

  // epilogue: join the hi-pair's li, normalize, write fp32, absmax
  li += __shfl_xor(li, 32);
  const float invl = 1.0f / li;
  float lmax = 0.f;
  float* orow = out + qkbase + (size_t)q * D_;
  #pragma unroll
  for (int db2 = 0; db2 < 2; db2++) {
    #pragma unroll
    for (int rg = 0; rg < 4; rg++) {
      float4 o;
      o.x = (db2 ? ao1[rg * 4 + 0] : ao0[rg * 4 + 0]) * invl;
      o.y = (db2 ? ao1[rg * 4 + 1] : ao0[rg * 4 + 1]) * invl;
      o.z = (db2 ? ao1[rg * 4 + 2] : ao0[rg * 4 + 2]) * invl;
      o.w = (db2 ? ao1[rg * 4 + 3] : ao0[rg * 4 + 3]) * invl;
      *(float4*)(orow + db2 * 32 + rg * 8 + hi * 4) = o;
      lmax = fmaxf(lmax, fmaxf(fmaxf(fabsf(o.x), fabsf(o.y)), fmaxf(fabsf(o.z), fabsf(o.w))));
    }
  }
  #pragma unroll
  for (int o = 32; o; o >>= 1) lmax = fmaxf(lmax, __shfl_xor(lmax, o));
  if (lane == 0) red[wid] = lmax;
  __syncthreads();
  if (t == 0) atomicMaxF(slot, fmaxf(red[0], red[1]));
}

// ---------- launch ----------
extern "C" void kernel_launch(void* const* d_in, const int* in_sizes, int n_in,
                              void* d_out, int out_size, void* d_ws, size_t ws_size,
                              hipStream_t stream) {
  const float* hs   = (const float*)d_in[0];
  const float* mask = (const float*)d_in[1];
  const float* wq = (const float*)d_in[2];  const float* bq = (const float*)d_in[3];
  const float* wk = (const float*)d_in[4];  const float* bk = (const float*)d_in[5];
  const float* wv = (const float*)d_in[6];  const float* bv = (const float*)d_in[7];
  const float* wo = (const float*)d_in[8];  const float* bo = (const float*)d_in[9];
  const float* w1 = (const float*)d_in[10]; const float* b1 = (const float*)d_in[11];
  const float* w2 = (const float*)d_in[12]; const float* b2 = (const float*)d_in[13];
  const float* g1 = (const float*)d_in[14]; const float* be1 = (const float*)d_in[15];
  const float* g2 = (const float*)d_in[16]; const float* be2 = (const float*)d_in[17];
  const int* wbits = (const int*)d_in[18];
  const int* abits = (const int*)d_in[19];

  // workspace layout (bytes)
  char* ws = (char*)d_ws;
  size_t off = 0;
  float* scal = (float*)ws;                      off += 256;        // absmax slots
  float* maddg= (float*)(ws + off);              off += (size_t)NT * 4;       // (1-mask)*MSK2
  float* fbuf = (float*)(ws + off);              off += (size_t)NT * D_ * 4;  // attn out (fp32)
  i8*    qx   = (i8*)(ws + off);                 off += (size_t)NT * D_;      // act quant codes
  bf16*  qb   = (bf16*)(ws + off);               off += (size_t)NT * D_ * 2;
  bf16*  kbuf = (bf16*)(ws + off);               off += (size_t)NT * D_ * 2;
  bf16*  vbuf = (bf16*)(ws + off);               off += (size_t)NT * D_ * 2;  // holds V^T
  float* h2   = (float*)(ws + off);              off += (size_t)NT * D_ * 4;  // attn residual out
  bf16*  h1   = (bf16*)(ws + off);               off += (size_t)NT * I_ * 2;  // gelu out (bf16)
  i8*    h1q  = (i8*)(ws + off);                 off += (size_t)NT * I_;      // gelu quant codes
  i8*    wqq  = (i8*)(ws + off);                 off += (size_t)D_ * D_;
  i8*    wkq  = (i8*)(ws + off);                 off += (size_t)D_ * D_;
  i8*    wvq  = (i8*)(ws + off);                 off += (size_t)D_ * D_;
  i8*    woq  = (i8*)(ws + off);                 off += (size_t)D_ * D_;
  i8*    w1q  = (i8*)(ws + off);                 off += (size_t)I_ * D_;
  i8*    w2q  = (i8*)(ws + off);                 off += (size_t)D_ * I_;
  if (ws_size < off) return;  // insufficient workspace: fail cleanly

  // slots: 0 x1, 1 attn, 2 x2, 3 h1, 4..9 weights
  k_prep<<<NT / 256, 256, 0, stream>>>(mask, maddg, scal);

  const size_t nDD4 = (size_t)D_ * D_ / 4, nDI4 = (size_t)D_ * I_ / 4;
  WArgs wa;
  wa.w[0] = wq; wa.w[1] = wk; wa.w[2] = wv; wa.w[3] = wo; wa.w[4] = w1; wa.w[5] = w2;
  wa.q[0] = wqq; wa.q[1] = wkq; wa.q[2] = wvq; wa.q[3] = woq; wa.q[4] = w1q; wa.q[5] = w2q;
  wa.n4[0] = nDD4; wa.n4[1] = nDD4; wa.n4[2] = nDD4; wa.n4[3] = nDD4;
  wa.n4[4] = nDI4; wa.n4[5] = nDI4;
  k_absmax6<<<dim3(1024, 1, 6), 256, 0, stream>>>(wa, scal + 4);
  k_quant6<<<dim3(1024, 1, 6), 256, 0, stream>>>(wa, scal + 4, wbits);

  const size_t nND4 = (size_t)NT * D_ / 4;

  // LN1 -> (cooperative fused) fake-quant(i8) -> fused QKV GEMM (V transposed)
  {
    const float* x_ = hs; const float* g_ = g1; const float* b_ = be1;
    i8* y_ = qx; float* s_ = scal + 0; const int* bits_ = abits;
    void* ka[] = {&x_, &g_, &b_, &y_, &s_, &bits_};
    hipLaunchCooperativeKernel((void*)k_lnq, dim3(NT / 4), dim3(256), ka, 0, stream);
  }
  {
    GemmArgs ga{};
    ga.A = qx; ga.B0 = wqq; ga.B1 = wkq; ga.B2 = wvq;
    ga.bias0 = bq; ga.bias1 = bk; ga.bias2 = bv;
    ga.out0 = qb; ga.out1 = kbuf; ga.out2 = vbuf;
    ga.sa = scal + 0; ga.sw0 = scal + 4; ga.sw1 = scal + 5; ga.sw2 = scal + 6;
    ga.abit = abits; ga.wbit = wbits;
    ga.K = D_; ga.ldc = D_;
    k_gqkv<<<(NT / 128) * (D_ / 128) * 3, 256, 0, stream>>>(ga);
  }

  // attention -> fake-quant(i8) -> out-proj (+residual)
  k_attn<<<dim3(S_ / 64, B_ * H_), 128, 0, stream>>>(qb, kbuf, vbuf, maddg, fbuf, scal + 1);
  k_quant<<<2048, 256, 0, stream>>>(fbuf, qx, scal + 1, abits, nND4);
  {
    GemmArgs ga{};
    ga.A = qx; ga.B0 = woq; ga.bias0 = bo; ga.out0 = h2; ga.res = hs;
    ga.sa = scal + 1; ga.sw0 = scal + 7;
    ga.abit = abits; ga.wbit = wbits;
    ga.K = D_; ga.ldc = D_;
    k_gout<<<(NT / 64) * (D_ / 128), 256, 0, stream>>>(ga);
  }

  // LN2 -> (cooperative fused) fake-quant(i8) -> MLP1 -> qgelu -> MLP2
  {
    const float* x_ = h2; const float* g_ = g2; const float* b_ = be2;
    i8* y_ = qx; float* s_ = scal + 2; const int* bits_ = abits;
    void* ka[] = {&x_, &g_, &b_, &y_, &s_, &bits_};
    hipLaunchCooperativeKernel((void*)k_lnq, dim3(NT / 4), dim3(256), ka, 0, stream);
  }
  {
    GemmArgs ga{};
    ga.A = qx; ga.B0 = w1q; ga.bias0 = b1; ga.out0 = h1; ga.slot = scal + 3;
    ga.sa = scal + 2; ga.sw0 = scal + 8;
    ga.abit = abits; ga.wbit = wbits;
    ga.K = D_; ga.ldc = I_;
    k_gmlp1<<<(NT / 128) * (I_ / 128), 256, 0, stream>>>(ga);
  }
  k_qgelu<<<(NT * (size_t)I_ / 8 + 255) / 256, 256, 0, stream>>>(h1, h1q, scal + 3, abits,
                                                                 (size_t)NT * I_ / 8);
  {
    GemmArgs ga{};
    ga.A = h1q; ga.B0 = w2q; ga.bias0 = b2; ga.out0 = d_out; ga.res = h2;
    ga.sa = scal + 3; ga.sw0 = scal + 9;
    ga.abit = abits; ga.wbit = wbits;
    ga.K = I_; ga.ldc = D_;
    k_gmlp2<<<(NT / 64) * (D_ / 128), 256, 0, stream>>>(ga);
  }
}

// Round 13
// 418.031 us; speedup vs baseline: 1.3022x; 1.3022x over previous
//
#include <hip/hip_runtime.h>
#include <hip/hip_bf16.h>
#include <math.h>

typedef __bf16 bf16;
typedef signed char i8;
typedef __bf16 bf16x8 __attribute__((ext_vector_type(8)));
typedef __bf16 bf16x4 __attribute__((ext_vector_type(4)));
typedef signed char i8x4 __attribute__((ext_vector_type(4)));
typedef signed char i8x8 __attribute__((ext_vector_type(8)));
typedef int    i32x4 __attribute__((ext_vector_type(4)));
typedef float  f32x4  __attribute__((ext_vector_type(4)));
typedef float  f32x16 __attribute__((ext_vector_type(16)));
typedef unsigned int u32x4 __attribute__((ext_vector_type(4)));

static constexpr int B_  = 2;
static constexpr int S_  = 2048;
static constexpr int D_  = 1024;
static constexpr int H_  = 16;
static constexpr int HD_ = 64;
static constexpr int I_  = 4096;
static constexpr int NT  = B_ * S_;       // 4096 tokens

// ---------- helpers ----------
__device__ __forceinline__ void atomicMaxF(float* p, float v) {
  atomicMax((unsigned int*)p, __float_as_uint(v));   // v >= 0 always
}

__device__ __forceinline__ f32x16 mfma32(bf16x8 a, bf16x8 b, f32x16 c) {
  return __builtin_amdgcn_mfma_f32_32x32x16_bf16(a, b, c, 0, 0, 0);
}

__device__ __forceinline__ i32x4 mfma_i8(i32x4 a, i32x4 b, i32x4 c) {
  return __builtin_amdgcn_mfma_i32_16x16x64_i8(a, b, c, 0, 0, 0);
}

__device__ __forceinline__ void gload16(const void* g, void* lds) {
  __builtin_amdgcn_global_load_lds(
      (const __attribute__((address_space(1))) void*)g,
      (__attribute__((address_space(3))) void*)lds, 16, 0, 0);
}

__device__ __forceinline__ i8 quantn(float x, float scale, float qmax) {
  return (i8)(int)rintf(fminf(fmaxf(x / scale, -qmax), qmax));
}

// Abramowitz-Stegun 7.1.26 erf: |err| <= 1.5e-7 (vs quant bin ~0.2 -> safe);
// ~12 VALU + 1 exp2 vs libm erff's ~25-35 ops.  Used in the MLP1 epilogue.
__device__ __forceinline__ float fast_erf(float x) {
  const float ax = fabsf(x);
  const float t = 1.0f / (1.0f + 0.3275911f * ax);
  const float p = t * (0.254829592f + t * (-0.284496736f + t * (1.421413741f +
                  t * (-1.453152027f + t * 1.061405429f))));
  const float r = 1.0f - p * exp2f(-ax * ax * 1.4426950408889634f);
  return copysignf(r, x);
}

// stage a 64x64 bf16 tile into LDS with a 128-thread block; XOR swizzle
// (chunk ^= row&7) applied on the GLOBAL source, LDS dest stays linear.
__device__ __forceinline__ void stage64b(const bf16* __restrict__ g, int rs, bf16* lds, int t) {
  #pragma unroll
  for (int r = 0; r < 4; r++) {
    const int cl  = r * 128 + t;           // 16B-chunk id in tile (512 total)
    const int row = cl >> 3;               // 8 chunks per 128B row
    const int scr = (cl & 7) ^ (row & 7);  // pre-swizzled source chunk
    gload16(g + (size_t)row * rs + scr * 8,
            (char*)lds + (size_t)(r * 128 + (t & 64)) * 16);
  }
}

// ---------- madd precompute + scalar-slot init ----------
__global__ __launch_bounds__(256) void k_prep(const float* __restrict__ mask,
                                              float* __restrict__ madd, float* __restrict__ scal) {
  constexpr float MSK2 = -14426.950408889634f;   // -10000 * log2(e)
  const int i = blockIdx.x * 256 + threadIdx.x;
  if (blockIdx.x == 0 && threadIdx.x < 32) scal[threadIdx.x] = 0.f;
  if (i < B_ * S_) madd[i] = (1.0f - mask[i]) * MSK2;
}

// ---------- fused per-tensor absmax + quant for the 6 weights (i8 out) -------
struct WArgs {
  const float* w[6];
  i8* q[6];
  size_t n4[6];
};

__global__ __launch_bounds__(256) void k_absmax6(WArgs a, float* __restrict__ slots) {
  const int z = blockIdx.z;
  const float* __restrict__ x = a.w[z];
  const size_t n4 = a.n4[z];
  size_t i = (size_t)blockIdx.x * 256 + threadIdx.x;
  const size_t stride = (size_t)gridDim.x * 256;
  float m = 0.f;
  for (; i < n4; i += stride) {
    float4 v = ((const float4*)x)[i];
    m = fmaxf(m, fmaxf(fmaxf(fabsf(v.x), fabsf(v.y)), fmaxf(fabsf(v.z), fabsf(v.w))));
  }
  #pragma unroll
  for (int o = 32; o; o >>= 1) m = fmaxf(m, __shfl_xor(m, o));
  __shared__ float red[4];
  if ((threadIdx.x & 63) == 0) red[threadIdx.x >> 6] = m;
  __syncthreads();
  if (threadIdx.x == 0)
    atomicMaxF(slots + z, fmaxf(fmaxf(red[0], red[1]), fmaxf(red[2], red[3])));
}

__global__ __launch_bounds__(256) void k_quant6(WArgs a, const float* __restrict__ slots,
                                                const int* __restrict__ bits) {
  const int z = blockIdx.z;
  const float* __restrict__ x = a.w[z];
  i8* __restrict__ y = a.q[z];
  const size_t n4 = a.n4[z];
  const float qmax  = (float)((1 << (*bits - 1)) - 1);
  const float scale = fmaxf(slots[z], 1e-8f) / qmax;
  size_t i = (size_t)blockIdx.x * 256 + threadIdx.x;
  const size_t stride = (size_t)gridDim.x * 256;
  for (; i < n4; i += stride) {
    float4 v = ((const float4*)x)[i];
    i8x4 o;
    o[0] = quantn(v.x, scale, qmax);
    o[1] = quantn(v.y, scale, qmax);
    o[2] = quantn(v.z, scale, qmax);
    o[3] = quantn(v.w, scale, qmax);
    ((i8x4*)y)[i] = o;
  }
}

// ---------- fake-quant fp32 -> i8 codes (activations) ----------
__global__ __launch_bounds__(256) void k_quant(const float* __restrict__ x, i8* __restrict__ y,
                                               const float* __restrict__ slot,
                                               const int* __restrict__ bits, size_t n4) {
  const float qmax  = (float)((1 << (*bits - 1)) - 1);
  const float scale = fmaxf(*slot, 1e-8f) / qmax;
  size_t i = (size_t)blockIdx.x * 256 + threadIdx.x;
  const size_t stride = (size_t)gridDim.x * 256;
  for (; i < n4; i += stride) {
    float4 v = ((const float4*)x)[i];
    i8x4 o;
    o[0] = quantn(v.x, scale, qmax);
    o[1] = quantn(v.y, scale, qmax);
    o[2] = quantn(v.z, scale, qmax);
    o[3] = quantn(v.w, scale, qmax);
    ((i8x4*)y)[i] = o;
  }
}

// ---------- fake-quant bf16 (GELU out) -> i8 codes ----------
__global__ __launch_bounds__(256) void k_qgelu(const bf16* __restrict__ x, i8* __restrict__ y,
                                               const float* __restrict__ slot,
                                               const int* __restrict__ bits, size_t n8) {
  const float qmax  = (float)((1 << (*bits - 1)) - 1);
  const float scale = fmaxf(*slot, 1e-8f) / qmax;
  size_t i = (size_t)blockIdx.x * 256 + threadIdx.x;
  if (i >= n8) return;
  bf16x8 v = ((const bf16x8*)x)[i];
  i8x8 o;
  #pragma unroll
  for (int j = 0; j < 8; j++) o[j] = quantn((float)v[j], scale, qmax);
  ((i8x8*)y)[i] = o;
}

// ---------- LayerNorm (fp32 out, + absmax) : one block per row ----------
__global__ __launch_bounds__(256) void k_ln(const float* __restrict__ x, const float* __restrict__ g,
                                            const float* __restrict__ be, float* __restrict__ y,
                                            float* __restrict__ slot) {
  const int row = blockIdx.x, t = threadIdx.x;
  const float4 v = ((const float4*)(x + (size_t)row * D_))[t];
  float s = v.x + v.y + v.z + v.w;
  float q = v.x * v.x + v.y * v.y + v.z * v.z + v.w * v.w;
  #pragma unroll
  for (int o = 32; o; o >>= 1) { s += __shfl_xor(s, o); q += __shfl_xor(q, o); }
  __shared__ float red[8];
  const int wid = t >> 6;
  if ((t & 63) == 0) { red[wid] = s; red[4 + wid] = q; }
  __syncthreads();
  s = red[0] + red[1] + red[2] + red[3];
  q = red[4] + red[5] + red[6] + red[7];
  const float mean = s * (1.f / D_);
  const float rstd = rsqrtf(q * (1.f / D_) - mean * mean + 1e-5f);
  const float4 gv = ((const float4*)g)[t];
  const float4 bv = ((const float4*)be)[t];
  float4 o;
  o.x = (v.x - mean) * rstd * gv.x + bv.x;
  o.y = (v.y - mean) * rstd * gv.y + bv.y;
  o.z = (v.z - mean) * rstd * gv.z + bv.z;
  o.w = (v.w - mean) * rstd * gv.w + bv.w;
  ((float4*)(y + (size_t)row * D_))[t] = o;
  float m = fmaxf(fmaxf(fabsf(o.x), fabsf(o.y)), fmaxf(fabsf(o.z), fabsf(o.w)));
  #pragma unroll
  for (int oo = 32; oo; oo >>= 1) m = fmaxf(m, __shfl_xor(m, oo));
  __syncthreads();                 // red reuse
  if ((t & 63) == 0) red[wid] = m;
  __syncthreads();
  if (t == 0) atomicMaxF(slot, fmaxf(fmaxf(red[0], red[1]), fmaxf(red[2], red[3])));
}

// ---------- int8 GEMM body (round-10 proven): C = (A@B^T)*s_a*s_w + bias -----
// tile (MT*32)x128, BK=128 i8, 4 waves 2x2, double-buffered (stage t+1 before
// compute t, one barrier/step).  T2 chunk XOR-swizzle on the GLOBAL source.
// bx/by/bz decoded per call-site for XCD-aware L2 locality (XCD = bid%8).
struct GemmArgs {
  const i8* A;
  const i8* B0; const i8* B1; const i8* B2;
  const float* bias0; const float* bias1; const float* bias2;
  void* out0; void* out1; void* out2;
  const float* res;   // MODE 1: residual (fp32, same layout as out)
  float* slot;        // MODE 2: absmax slot
  const float* sa;                                   // activation absmax slot
  const float* sw0; const float* sw1; const float* sw2;  // weight absmax slots
  const int* abit; const int* wbit;
  int K; int ldc;
};

template <int MODE, int MT>
__device__ __forceinline__ void gemm_body(GemmArgs a, int bx, int by, int bz) {
  constexpr int TM = MT * 32;
  __shared__ __align__(16) i8 As[2][TM * 128];
  __shared__ __align__(16) i8 Bs[2][128 * 128];
  const int t = threadIdx.x, wid = t >> 6, lane = t & 63;
  const int grp = lane >> 4, l15 = lane & 15;
  const int wm = wid >> 1, wn = wid & 1;
  const size_t m0 = (size_t)bx * TM, n0 = (size_t)by * 128;
  const int K = a.K, ldc = a.ldc;

  const i8* Bw; const float* bias; void* outv; const float* swp;
  if constexpr (MODE == 0) {
    Bw   = bz == 0 ? a.B0 : (bz == 1 ? a.B1 : a.B2);
    bias = bz == 0 ? a.bias0 : (bz == 1 ? a.bias1 : a.bias2);
    outv = bz == 0 ? a.out0 : (bz == 1 ? a.out1 : a.out2);
    swp  = bz == 0 ? a.sw0 : (bz == 1 ? a.sw1 : a.sw2);
  } else {
    Bw = a.B0; bias = a.bias0; outv = a.out0; swp = a.sw0;
  }
  const float qa = (float)((1 << (*a.abit - 1)) - 1);
  const float qw = (float)((1 << (*a.wbit - 1)) - 1);
  const float sasw = (fmaxf(*a.sa, 1e-8f) / qa) * (fmaxf(*swp, 1e-8f) / qw);

  i32x4 acc[MT][4];
  #pragma unroll
  for (int m = 0; m < MT; m++)
    #pragma unroll
    for (int n = 0; n < 4; n++) acc[m][n] = i32x4{0, 0, 0, 0};

  auto stage = [&](int kt, int buf) {
    #pragma unroll
    for (int r = 0; r < MT; r++) {
      const int cl = r * 256 + t;
      const int row = cl >> 3, c = cl & 7;
      gload16(a.A + (m0 + row) * (size_t)K + kt + ((c ^ (row & 7)) * 16),
              (char*)&As[buf][0] + (size_t)(r * 256 + (t & 192)) * 16);
    }
    #pragma unroll
    for (int r = 0; r < 4; r++) {
      const int cl = r * 256 + t;
      const int row = cl >> 3, c = cl & 7;
      gload16(Bw + (n0 + row) * (size_t)K + kt + ((c ^ (row & 7)) * 16),
              (char*)&Bs[buf][0] + (size_t)(r * 256 + (t & 192)) * 16);
    }
  };

  stage(0, 0);
  __syncthreads();           // tile 0 resident
  int cur = 0;
  for (int kt = 0; kt < K; kt += 128) {
    if (kt + 128 < K) stage(kt + 128, cur ^ 1);  // prefetch next (covered by MFMA)
    #pragma unroll
    for (int ks = 0; ks < 2; ks++) {
      i32x4 bfv[4];
      #pragma unroll
      for (int n = 0; n < 4; n++) {
        const int rb = wn * 64 + n * 16 + l15;
        bfv[n] = *(const i32x4*)(&Bs[cur][0] + rb * 128 + (((ks * 4 + grp) ^ (rb & 7)) * 16));
      }
      #pragma unroll
      for (int m = 0; m < MT; m++) {
        const int ra = wm * (MT * 16) + m * 16 + l15;
        const i32x4 af = *(const i32x4*)(&As[cur][0] + ra * 128 + (((ks * 4 + grp) ^ (ra & 7)) * 16));
        #pragma unroll
        for (int n = 0; n < 4; n++)
          acc[m][n] = mfma_i8(af, bfv[n], acc[m][n]);
      }
    }
    __syncthreads();         // drains prefetch (vmcnt) + protects cur for rotate
    cur ^= 1;
  }

  // epilogue: C/D frag layout: row=(lane>>4)*4+i, col=lane&15
  const size_t gr0 = m0 + wm * (MT * 16) + grp * 4;
  const size_t gc0 = n0 + wn * 64 + l15;

  if constexpr (MODE == 0) {
    if (bz == 2) {
      // V^T store: out[b][gc][s] packed bf16x4 along s (i dimension)
      #pragma unroll
      for (int n = 0; n < 4; n++) {
        const size_t gc = gc0 + n * 16;
        const float bc = bias[gc];
        #pragma unroll
        for (int m = 0; m < MT; m++) {
          const size_t gr = gr0 + m * 16;              // tokens gr..gr+3, same batch
          const size_t bb = gr >> 11, s0 = gr & (S_ - 1);
          bf16x4 vv;
          #pragma unroll
          for (int i = 0; i < 4; i++) vv[i] = (bf16)((float)acc[m][n][i] * sasw + bc);
          *(bf16x4*)((bf16*)outv + bb * (size_t)D_ * S_ + gc * S_ + s0) = vv;
        }
      }
      return;
    }
  }

  float lmax = 0.f;
  #pragma unroll
  for (int n = 0; n < 4; n++) {
    const size_t gc = gc0 + n * 16;
    const float bc = bias[gc];
    #pragma unroll
    for (int m = 0; m < MT; m++) {
      const size_t gr = gr0 + m * 16;
      #pragma unroll
      for (int i = 0; i < 4; i++) {
        const float v = (float)acc[m][n][i] * sasw + bc;
        const size_t idx = (gr + i) * (size_t)ldc + gc;
        if constexpr (MODE == 0) {
          ((bf16*)outv)[idx] = (bf16)v;
        } else if constexpr (MODE == 1) {
          ((float*)outv)[idx] = v + a.res[idx];
        } else {
          const float gl = 0.5f * v * (1.0f + fast_erf(v * 0.7071067811865475f));
          ((bf16*)outv)[idx] = (bf16)gl;
          lmax = fmaxf(lmax, fabsf(gl));
        }
      }
    }
  }
  if constexpr (MODE == 2) {
    #pragma unroll
    for (int o = 32; o; o >>= 1) lmax = fmaxf(lmax, __shfl_xor(lmax, o));
    float* red = (float*)&As[0][0];     // LDS reuse (k-loop done)
    if (lane == 0) red[wid] = lmax;
    __syncthreads();
    if (t == 0) atomicMaxF(a.slot, fmaxf(fmaxf(red[0], red[1]), fmaxf(red[2], red[3])));
  }
}

// Per-call-site wrappers: named for rocprof attribution; 1-D grid; block
// decode pins XCD (= bid%8) to an L2-resident working set.
__global__ __launch_bounds__(256) void k_gqkv(GemmArgs a) {
  const int d = blockIdx.x, c = d & 7, s = d >> 3;   // s in [0,96)
  gemm_body<0, 4>(a, s / 3, c, s % 3);
}
__global__ __launch_bounds__(256) void k_gout(GemmArgs a) {
  const int d = blockIdx.x, c = d & 7, s = d >> 3;   // s in [0,64)
  gemm_body<1, 2>(a, s, c, 0);
}
__global__ __launch_bounds__(256) void k_gmlp1(GemmArgs a) {
  const int d = blockIdx.x, c = d & 7, s = d >> 3;   // s in [0,128)
  gemm_body<2, 4>(a, s >> 2, c * 4 + (s & 3), 0);
}
__global__ __launch_bounds__(256) void k_gmlp2(GemmArgs a) {
  const int d = blockIdx.x, c = d & 7, s = d >> 3;   // s in [0,64)
  gemm_body<1, 2>(a, ((c >> 2) << 5) | (s >> 1), ((c & 3) << 1) | (s & 1), 0);
}

// ---------- fused attention (round-10 structure + XCD-pinned bh decode) ------
// 2 waves x 32 q; KV tile 64 double-buffered; swapped QK (mfma(K,Q)) -> scores
// lane-local, in-register softmax, defer-max (T13), cvt_pk+permlane pack (T12),
// swapped PV (mfma(V^T,P)).  1-D grid: XCD c owns bh in {4c..4c+3} -> that
// XCD's L2 keeps 4 heads' K/V (2MB) resident instead of all-XCD replication.
__global__ __launch_bounds__(128) void k_attn(const bf16* __restrict__ qb, const bf16* __restrict__ kb,
                                              const bf16* __restrict__ vt, const float* __restrict__ madd,
                                              float* __restrict__ out, float* __restrict__ slot) {
  constexpr float SCL2 = 0.18033688011112042f;   // 0.125 * log2(e)  (exp2 domain)
  constexpr float THR  = 8.0f;                   // defer-max threshold (log2 units)
  __shared__ __align__(16) bf16 Ks[2][64 * 64];  // [buf][key][d]  (chunk-swizzled)
  __shared__ __align__(16) bf16 Vs[2][64 * 64];  // [buf][d][key]  (chunk-swizzled)
  __shared__ float red[2];
  const int t = threadIdx.x, wid = t >> 6, lane = t & 63;
  const int l31 = lane & 31, hi = lane >> 5;
  const int d = blockIdx.x, c = d & 7, s = d >> 3;      // s in [0,128)
  const int bh = c * 4 + (s & 3), qt = s >> 2;          // XCD-pinned head group
  const int b = bh >> 4, h = bh & 15;                   // H = 16
  const size_t qkbase = ((size_t)b * S_) * D_ + (size_t)h * HD_;
  const size_t vtbase = (size_t)b * D_ * S_ + (size_t)h * HD_ * S_;
  const int q = qt * 64 + wid * 32 + l31;               // this lane's q-row

  bf16x8 qf[4];
  #pragma unroll
  for (int j = 0; j < 4; j++)
    qf[j] = *(const bf16x8*)(qb + qkbase + (size_t)q * D_ + j * 16 + hi * 8);

  f32x16 ao0, ao1;
  #pragma unroll
  for (int r = 0; r < 16; r++) { ao0[r] = 0.f; ao1[r] = 0.f; }
  float mi = -INFINITY, li = 0.f;

  stage64b(kb + qkbase, D_, Ks[0], t);
  stage64b(vt + vtbase, S_, Vs[0], t);
  __syncthreads();
  int cur = 0;

  const float* mp = madd + (size_t)b * S_ + hi * 4;

  for (int kt0 = 0; kt0 < S_; kt0 += 64) {
    // madd loads FIRST (vmcnt-oldest), fence, then prefetch
    f32x4 mv[2][4];
    #pragma unroll
    for (int kb2 = 0; kb2 < 2; kb2++)
      #pragma unroll
      for (int g = 0; g < 4; g++)
        mv[kb2][g] = *(const f32x4*)(mp + kt0 + kb2 * 32 + g * 8);
    __builtin_amdgcn_sched_barrier(0);
    if (kt0 + 64 < S_) {
      stage64b(kb + qkbase + (size_t)(kt0 + 64) * D_, D_, Ks[cur ^ 1], t);
      stage64b(vt + vtbase + (kt0 + 64), S_, Vs[cur ^ 1], t);
    }

    // QK^T swapped: D[row=key][col=q]
    f32x16 s0, s1;
    #pragma unroll
    for (int r = 0; r < 16; r++) { s0[r] = 0.f; s1[r] = 0.f; }
    #pragma unroll
    for (int j = 0; j < 4; j++) {
      const int ch = (j * 2 + hi);
      const bf16x8 kf0 = *(const bf16x8*)(&Ks[cur][0] + l31 * 64 + ((ch ^ (l31 & 7)) * 8));
      const bf16x8 kf1 = *(const bf16x8*)(&Ks[cur][0] + (32 + l31) * 64 + ((ch ^ (l31 & 7)) * 8));
      s0 = mfma32(kf0, qf[j], s0);
      s1 = mfma32(kf1, qf[j], s1);
    }

    float pv_[32];
    #pragma unroll
    for (int r = 0; r < 16; r++) pv_[r]      = s0[r] * SCL2 + mv[0][r >> 2][r & 3];
    #pragma unroll
    for (int r = 0; r < 16; r++) pv_[16 + r] = s1[r] * SCL2 + mv[1][r >> 2][r & 3];

    float mx = pv_[0];
    #pragma unroll
    for (int r = 1; r < 32; r++) mx = fmaxf(mx, pv_[r]);
    mx = fmaxf(mx, __shfl_xor(mx, 32));

    if (!__all(mx - mi <= THR)) {        // defer-max
      const float mnew = fmaxf(mi, mx);
      const float co = exp2f(mi - mnew);
      li *= co;
      #pragma unroll
      for (int r = 0; r < 16; r++) { ao0[r] *= co; ao1[r] *= co; }
      mi = mnew;
    }

    float ls = 0.f;
    #pragma unroll
    for (int r = 0; r < 32; r++) { pv_[r] = exp2f(pv_[r] - mi); ls += pv_[r]; }
    li += ls;

    unsigned pk[16];
    #pragma unroll
    for (int tt = 0; tt < 8; tt++) {
      asm("v_cvt_pk_bf16_f32 %0, %1, %2" : "=v"(pk[tt])     : "v"(pv_[2 * tt]),      "v"(pv_[2 * tt + 1]));
      asm("v_cvt_pk_bf16_f32 %0, %1, %2" : "=v"(pk[8 + tt]) : "v"(pv_[16 + 2 * tt]), "v"(pv_[16 + 2 * tt + 1]));
    }
    #pragma unroll
    for (int g = 0; g < 4; g++) {
      asm volatile("v_permlane32_swap_b32 %0, %1" : "+v"(pk[4 * g]),     "+v"(pk[4 * g + 2]));
      asm volatile("v_permlane32_swap_b32 %0, %1" : "+v"(pk[4 * g + 1]), "+v"(pk[4 * g + 3]));
    }

    #pragma unroll
    for (int j = 0; j < 4; j++) {
      const u32x4 w = {pk[4 * j], pk[4 * j + 1], pk[4 * j + 2], pk[4 * j + 3]};
      const bf16x8 pf = __builtin_bit_cast(bf16x8, w);
      const int ch = (j * 2 + hi);
      const bf16x8 vf0 = *(const bf16x8*)(&Vs[cur][0] + l31 * 64 + ((ch ^ (l31 & 7)) * 8));
      const bf16x8 vf1 = *(const bf16x8*)(&Vs[cur][0] + (32 + l31) * 64 + ((ch ^ (l31 & 7)) * 8));
      ao0 = mfma32(vf0, pf, ao0);
      ao1 = mfma32(vf1, pf, ao1);
    }
    __syncthreads();   // prefetch landed + all waves done reading cur
    cur ^= 1;
  }

  // epilogue: join the hi-pair's li, normalize, write fp32, absmax
  li += __shfl_xor(li, 32);
  const float invl = 1.0f / li;
  float lmax = 0.f;
  float* orow = out + qkbase + (size_t)q * D_;
  #pragma unroll
  for (int db2 = 0; db2 < 2; db2++) {
    #pragma unroll
    for (int rg = 0; rg < 4; rg++) {
      float4 o;
      o.x = (db2 ? ao1[rg * 4 + 0] : ao0[rg * 4 + 0]) * invl;
      o.y = (db2 ? ao1[rg * 4 + 1] : ao0[rg * 4 + 1]) * invl;
      o.z = (db2 ? ao1[rg * 4 + 2] : ao0[rg * 4 + 2]) * invl;
      o.w = (db2 ? ao1[rg * 4 + 3] : ao0[rg * 4 + 3]) * invl;
      *(float4*)(orow + db2 * 32 + rg * 8 + hi * 4) = o;
      lmax = fmaxf(lmax, fmaxf(fmaxf(fabsf(o.x), fabsf(o.y)), fmaxf(fabsf(o.z), fabsf(o.w))));
    }
  }
  #pragma unroll
  for (int o = 32; o; o >>= 1) lmax = fmaxf(lmax, __shfl_xor(lmax, o));
  if (lane == 0) red[wid] = lmax;
  __syncthreads();
  if (t == 0) atomicMaxF(slot, fmaxf(red[0], red[1]));
}

// ---------- launch ----------
extern "C" void kernel_launch(void* const* d_in, const int* in_sizes, int n_in,
                              void* d_out, int out_size, void* d_ws, size_t ws_size,
                              hipStream_t stream) {
  const float* hs   = (const float*)d_in[0];
  const float* mask = (const float*)d_in[1];
  const float* wq = (const float*)d_in[2];  const float* bq = (const float*)d_in[3];
  const float* wk = (const float*)d_in[4];  const float* bk = (const float*)d_in[5];
  const float* wv = (const float*)d_in[6];  const float* bv = (const float*)d_in[7];
  const float* wo = (const float*)d_in[8];  const float* bo = (const float*)d_in[9];
  const float* w1 = (const float*)d_in[10]; const float* b1 = (const float*)d_in[11];
  const float* w2 = (const float*)d_in[12]; const float* b2 = (const float*)d_in[13];
  const float* g1 = (const float*)d_in[14]; const float* be1 = (const float*)d_in[15];
  const float* g2 = (const float*)d_in[16]; const float* be2 = (const float*)d_in[17];
  const int* wbits = (const int*)d_in[18];
  const int* abits = (const int*)d_in[19];

  // workspace layout (bytes)
  char* ws = (char*)d_ws;
  size_t off = 0;
  float* scal = (float*)ws;                      off += 256;        // absmax slots
  float* maddg= (float*)(ws + off);              off += (size_t)NT * 4;       // (1-mask)*MSK2
  float* fbuf = (float*)(ws + off);              off += (size_t)NT * D_ * 4;  // x1f/attnf/x2f
  i8*    qx   = (i8*)(ws + off);                 off += (size_t)NT * D_;      // act quant codes
  bf16*  qb   = (bf16*)(ws + off);               off += (size_t)NT * D_ * 2;
  bf16*  kbuf = (bf16*)(ws + off);               off += (size_t)NT * D_ * 2;
  bf16*  vbuf = (bf16*)(ws + off);               off += (size_t)NT * D_ * 2;  // holds V^T
  float* h2   = (float*)(ws + off);              off += (size_t)NT * D_ * 4;  // attn residual out
  bf16*  h1   = (bf16*)(ws + off);               off += (size_t)NT * I_ * 2;  // gelu out (bf16)
  i8*    h1q  = (i8*)(ws + off);                 off += (size_t)NT * I_;      // gelu quant codes
  i8*    wqq  = (i8*)(ws + off);                 off += (size_t)D_ * D_;
  i8*    wkq  = (i8*)(ws + off);                 off += (size_t)D_ * D_;
  i8*    wvq  = (i8*)(ws + off);                 off += (size_t)D_ * D_;
  i8*    woq  = (i8*)(ws + off);                 off += (size_t)D_ * D_;
  i8*    w1q  = (i8*)(ws + off);                 off += (size_t)I_ * D_;
  i8*    w2q  = (i8*)(ws + off);                 off += (size_t)D_ * I_;
  if (ws_size < off) return;  // insufficient workspace: fail cleanly

  // slots: 0 x1, 1 attn, 2 x2, 3 h1, 4..9 weights
  k_prep<<<NT / 256, 256, 0, stream>>>(mask, maddg, scal);

  const size_t nDD4 = (size_t)D_ * D_ / 4, nDI4 = (size_t)D_ * I_ / 4;
  WArgs wa;
  wa.w[0] = wq; wa.w[1] = wk; wa.w[2] = wv; wa.w[3] = wo; wa.w[4] = w1; wa.w[5] = w2;
  wa.q[0] = wqq; wa.q[1] = wkq; wa.q[2] = wvq; wa.q[3] = woq; wa.q[4] = w1q; wa.q[5] = w2q;
  wa.n4[0] = nDD4; wa.n4[1] = nDD4; wa.n4[2] = nDD4; wa.n4[3] = nDD4;
  wa.n4[4] = nDI4; wa.n4[5] = nDI4;
  k_absmax6<<<dim3(1024, 1, 6), 256, 0, stream>>>(wa, scal + 4);
  k_quant6<<<dim3(1024, 1, 6), 256, 0, stream>>>(wa, scal + 4, wbits);

  const size_t nND4 = (size_t)NT * D_ / 4;

  // LN1 -> fake-quant(i8) -> fused QKV GEMM (V written transposed)
  k_ln<<<NT, 256, 0, stream>>>(hs, g1, be1, fbuf, scal + 0);
  k_quant<<<2048, 256, 0, stream>>>(fbuf, qx, scal + 0, abits, nND4);
  {
    GemmArgs ga{};
    ga.A = qx; ga.B0 = wqq; ga.B1 = wkq; ga.B2 = wvq;
    ga.bias0 = bq; ga.bias1 = bk; ga.bias2 = bv;
    ga.out0 = qb; ga.out1 = kbuf; ga.out2 = vbuf;
    ga.sa = scal + 0; ga.sw0 = scal + 4; ga.sw1 = scal + 5; ga.sw2 = scal + 6;
    ga.abit = abits; ga.wbit = wbits;
    ga.K = D_; ga.ldc = D_;
    k_gqkv<<<(NT / 128) * (D_ / 128) * 3, 256, 0, stream>>>(ga);
  }

  // attention -> fake-quant(i8) -> out-proj (+residual)
  k_attn<<<(S_ / 64) * B_ * H_, 128, 0, stream>>>(qb, kbuf, vbuf, maddg, fbuf, scal + 1);
  k_quant<<<2048, 256, 0, stream>>>(fbuf, qx, scal + 1, abits, nND4);
  {
    GemmArgs ga{};
    ga.A = qx; ga.B0 = woq; ga.bias0 = bo; ga.out0 = h2; ga.res = hs;
    ga.sa = scal + 1; ga.sw0 = scal + 7;
    ga.abit = abits; ga.wbit = wbits;
    ga.K = D_; ga.ldc = D_;
    k_gout<<<(NT / 64) * (D_ / 128), 256, 0, stream>>>(ga);
  }

  // LN2 -> fake-quant(i8) -> MLP1 (gelu + absmax) -> fake-quant(i8) -> MLP2
  k_ln<<<NT, 256, 0, stream>>>(h2, g2, be2, fbuf, scal + 2);
  k_quant<<<2048, 256, 0, stream>>>(fbuf, qx, scal + 2, abits, nND4);
  {
    GemmArgs ga{};
    ga.A = qx; ga.B0 = w1q; ga.bias0 = b1; ga.out0 = h1; ga.slot = scal + 3;
    ga.sa = scal + 2; ga.sw0 = scal + 8;
    ga.abit = abits; ga.wbit = wbits;
    ga.K = D_; ga.ldc = I_;
    k_gmlp1<<<(NT / 128) * (I_ / 128), 256, 0, stream>>>(ga);
  }
  k_qgelu<<<(NT * (size_t)I_ / 8 + 255) / 256, 256, 0, stream>>>(h1, h1q, scal + 3, abits,
                                                                 (size_t)NT * I_ / 8);
  {
    GemmArgs ga{};
    ga.A = h1q; ga.B0 = w2q; ga.bias0 = b2; ga.out0 = d_out; ga.res = h2;
    ga.sa = scal + 3; ga.sw0 = scal + 9;
    ga.abit = abits; ga.wbit = wbits;
    ga.K = I_; ga.ldc = D_;
    k_gmlp2<<<(NT / 64) * (D_ / 128), 256, 0, stream>>>(ga);
  }
}